// Round 15
// baseline (71.410 us; speedup 1.0000x reference)
//
#include <hip/hip_runtime.h>

// BinaryLinear int8 path (round 15):
//   prep    : fused {X f32 -> i8 per-row quant + Sc} and {W -> {0,1} i8, NxK}
//   gemm_pv2: r11's barrier-free wave-private-LDS structure + r12's VERIFIED
//             64-B-row swizzle (slot' = fg ^ ((fr>>1)&3); r11's conflicts
//             3.1M -> ~0). 256x256 tile, 8 waves, BK=64, 12 KB/wave private
//             LDS; per-wave vmcnt/lgkmcnt sync only -> waves de-phase, LDS
//             port pipelines across waves, MFMA hides underneath (m114).
//             mfma_i32_16x16x64_i8, f32 dequant epilogue.
// Fallback: round-1 fused bf16 kernel if ws too small.

#define MDIM 8192
#define NDIM 2048
#define KDIM 2048
#define NT   (KDIM / 64)          // 32 K-tiles of 64 i8

typedef __attribute__((ext_vector_type(8))) short short8;
typedef __attribute__((ext_vector_type(4))) float float4v;
typedef __attribute__((ext_vector_type(4))) float f32x4;
typedef __attribute__((ext_vector_type(4))) int int4v;
typedef __attribute__((ext_vector_type(4))) unsigned short ushort4v;
typedef __attribute__((ext_vector_type(8))) unsigned short ushort8v;

__device__ __forceinline__ unsigned short f2bf(float f) {
    union { float f; unsigned u; } v; v.f = f;
    unsigned r = v.u + 0x7FFFu + ((v.u >> 16) & 1u);
    return (unsigned short)(r >> 16);
}

__device__ __forceinline__ void gload_lds16(void* l, const void* g) {
    __builtin_amdgcn_global_load_lds(
        (const __attribute__((address_space(1))) unsigned int*)g,
        (__attribute__((address_space(3))) unsigned int*)l,
        16, 0, 0);
}

#define FENCE asm volatile("" ::: "memory")

// ---------------- pass 1 (fused): quantize X rows + binarize/transpose W ----
__global__ __launch_bounds__(256) void prep(const float* __restrict__ X,
                                            const float* __restrict__ W,
                                            signed char* __restrict__ Xq,
                                            signed char* __restrict__ Wt,
                                            float* __restrict__ Sc) {
    __shared__ __align__(16) signed char T[64][80];
    __shared__ float wm[4];
    const int t = threadIdx.x;
    const int bid = blockIdx.x;

    if (bid < MDIM) {
        const int row = bid;
        const float* xr = X + (size_t)row * KDIM + t * 8;
        float4v a = *reinterpret_cast<const float4v*>(xr);
        float4v b = *reinterpret_cast<const float4v*>(xr + 4);
        float m = fabsf(a[0]);
        m = fmaxf(m, fabsf(a[1])); m = fmaxf(m, fabsf(a[2])); m = fmaxf(m, fabsf(a[3]));
        m = fmaxf(m, fabsf(b[0])); m = fmaxf(m, fabsf(b[1]));
        m = fmaxf(m, fabsf(b[2])); m = fmaxf(m, fabsf(b[3]));
#pragma unroll
        for (int off = 32; off; off >>= 1)
            m = fmaxf(m, __shfl_xor(m, off));
        if ((t & 63) == 0) wm[t >> 6] = m;
        __syncthreads();
        const float s = fmaxf(fmaxf(wm[0], wm[1]), fmaxf(wm[2], wm[3]));
        const float inv = (s > 0.f) ? 127.0f / s : 0.f;

        int q[8];
        q[0] = __float2int_rn(a[0] * inv); q[1] = __float2int_rn(a[1] * inv);
        q[2] = __float2int_rn(a[2] * inv); q[3] = __float2int_rn(a[3] * inv);
        q[4] = __float2int_rn(b[0] * inv); q[5] = __float2int_rn(b[1] * inv);
        q[6] = __float2int_rn(b[2] * inv); q[7] = __float2int_rn(b[3] * inv);
        unsigned lo = (q[0] & 255) | ((q[1] & 255) << 8) | ((q[2] & 255) << 16) | ((unsigned)(q[3] & 255) << 24);
        unsigned hi = (q[4] & 255) | ((q[5] & 255) << 8) | ((q[6] & 255) << 16) | ((unsigned)(q[7] & 255) << 24);
        unsigned* dst = (unsigned*)(Xq + (size_t)row * KDIM + t * 8);
        dst[0] = lo; dst[1] = hi;
        if (t == 0) Sc[row] = s * (1.0f / 127.0f);
    } else {
        const int wb = bid - MDIM;
        const int k0 = (wb >> 5) * 64;
        const int n0 = (wb & 31) * 64;
        const int kr = t >> 4;
        const int nc = (t & 15) * 4;
#pragma unroll
        for (int rr = 0; rr < 4; ++rr) {
            int k = k0 + rr * 16 + kr;
            float4v w4 = *reinterpret_cast<const float4v*>(W + (size_t)k * NDIM + n0 + nc);
#pragma unroll
            for (int c = 0; c < 4; ++c)
                T[nc + c][rr * 16 + kr] = (w4[c] > 0.0f) ? (signed char)1 : (signed char)0;
        }
        __syncthreads();
        const int row = t >> 2, ch = t & 3;
        int4v v = *reinterpret_cast<const int4v*>(&T[row][ch * 16]);
        *reinterpret_cast<int4v*>(Wt + (size_t)(n0 + row) * KDIM + k0 + ch * 16) = v;
    }
}

// ---------------- pass 2: 256x256 i8 GEMM, wave-private LDS + swizzle ----
// Wave w (wr=w>>2, wc=w&3) owns LDS [w*12288, +12288): A 128 rows x 64 B at
// +0, B 64 rows x 64 B at +8192. 16-B slot s of row r holds global k-octet
// s ^ ((r>>1)&3)  [r12-verified swizzle: banks 2-way aliased = free].
// Store side: gload_lds dest linear (base + i*1024 + lane*16 = row (l>>2),
// phys slot (l&3)); source fetches global slot (l&3)^((l>>3)&3)  [rule #21].
// Read side: frag (fr,fg) reads phys slot fg^((fr>>1)&3).
// Per tile (no barriers anywhere): vmcnt(0) own stages; 12 ds_read_b128;
// lgkmcnt(0)+sched_barrier; stage t+1 (12 gload_lds); 32 MFMA (setprio).
__global__ __launch_bounds__(512, 1) void gemm_pv2(const signed char* __restrict__ A,
                                                   const signed char* __restrict__ Bt,
                                                   const float* __restrict__ Sc,
                                                   float* __restrict__ O) {
    extern __shared__ char lds[];
    const int tid  = threadIdx.x;
    const int lane = tid & 63;
    const int w    = tid >> 6;       // 0..7
    const int wr   = w >> 2;         // 0..1
    const int wc   = w & 3;          // 0..3

    int id  = blockIdx.x;            // 256 blocks, %8==0 -> bijective
    int swz = (id & 7) * 32 + (id >> 3);
    const int bm = swz >> 3;         // 0..31
    const int bn = swz & 7;          // 0..7

    char* base = lds + w * 12288;    // private region

    // staging source: lane l -> row (l>>2), pre-swizzled col ((l&3)^((l>>3)&3))*16
    const int lr = lane >> 2;
    const int lc = ((lane & 3) ^ ((lane >> 3) & 3)) << 4;
    const char* aS = (const char*)A + (size_t)(bm * 256 + wr * 128 + lr) * KDIM + lc;
    const char* bS = (const char*)Bt + (size_t)(bn * 256 + wc * 64 + lr) * KDIM + lc;

    // fragment read constants: row fr, phys slot fg ^ ((fr>>1)&3)
    const int fr = lane & 15, fg = lane >> 4;
    const int fOff = fr * 64 + ((fg ^ ((fr >> 1) & 3)) << 4);   // + mi*1024

    int4v acc[8][4];
#pragma unroll
    for (int i = 0; i < 8; ++i)
#pragma unroll
        for (int j = 0; j < 4; ++j) {
            acc[i][j][0] = 0; acc[i][j][1] = 0; acc[i][j][2] = 0; acc[i][j][3] = 0;
        }

    // prologue: stage tile 0
#pragma unroll
    for (int i = 0; i < 8; ++i)
        gload_lds16(base + i * 1024, aS + (size_t)i * 16 * KDIM);
#pragma unroll
    for (int j = 0; j < 4; ++j)
        gload_lds16(base + 8192 + j * 1024, bS + (size_t)j * 16 * KDIM);

    for (int t = 0; t < NT; ++t) {
        const bool more = (t + 1 < NT);
        const char* aN = aS + (size_t)(t + 1) * 64;
        const char* bN = bS + (size_t)(t + 1) * 64;

        // own staged loads landed (per-wave counter; no barrier)
        asm volatile("s_waitcnt vmcnt(0)" ::: "memory");

        // ---- frag reads (12 x ds_read_b128, conflict-free via swizzle) ----
        int4v af[8], bf[4];
#pragma unroll
        for (int mi = 0; mi < 8; ++mi)
            af[mi] = *reinterpret_cast<const int4v*>(base + mi * 1024 + fOff);
#pragma unroll
        for (int ni = 0; ni < 4; ++ni)
            bf[ni] = *reinterpret_cast<const int4v*>(base + 8192 + ni * 1024 + fOff);

        // all reads complete -> LDS region free for overwrite (rule #18 fence)
        asm volatile("s_waitcnt lgkmcnt(0)" ::: "memory");
        __builtin_amdgcn_sched_barrier(0);

        // ---- stage tile t+1 (overlaps MFMA below) ----
        if (more) {
#pragma unroll
            for (int i = 0; i < 8; ++i)
                gload_lds16(base + i * 1024, aN + (size_t)i * 16 * KDIM);
#pragma unroll
            for (int j = 0; j < 4; ++j)
                gload_lds16(base + 8192 + j * 1024, bN + (size_t)j * 16 * KDIM);
        }

        // ---- 32 MFMA ----
        __builtin_amdgcn_s_setprio(1);
#pragma unroll
        for (int mi = 0; mi < 8; ++mi)
#pragma unroll
            for (int ni = 0; ni < 4; ++ni)
                acc[mi][ni] = __builtin_amdgcn_mfma_i32_16x16x64_i8(
                    af[mi], bf[ni], acc[mi][ni], 0, 0, 0);
        __builtin_amdgcn_s_setprio(0);
        FENCE;
    }

    // ---- epilogue: C/D col = lane&15, row = 4*(lane>>4) + reg; dequant ----
    const int orow0 = bm * 256 + wr * 128 + fg * 4;
    const int ocol0 = bn * 256 + wc * 64 + fr;
#pragma unroll
    for (int mi = 0; mi < 8; ++mi)
#pragma unroll
        for (int r = 0; r < 4; ++r) {
            const int row = orow0 + mi * 16 + r;
            const float s = Sc[row];
            float* op = O + (size_t)row * NDIM + ocol0;
#pragma unroll
            for (int ni = 0; ni < 4; ++ni)
                op[ni * 16] = s * (float)acc[mi][ni][r];
        }
}

// ---------------- fallback: round-1 fused bf16 kernel ----------------
__global__ __launch_bounds__(256, 2) void binlin_fused(
        const float* __restrict__ X, const float* __restrict__ W,
        float* __restrict__ O) {
    const int tid = threadIdx.x;
    const int lane = tid & 63;
    const int wave = tid >> 6;
    const int wr = wave >> 1, wc = wave & 1;
    const int NWG = (MDIM / 128) * (NDIM / 128);
    int id = blockIdx.x;
    int swz = (id & 7) * (NWG >> 3) + (id >> 3);
    const int bm = swz >> 4, bn = swz & 15;

    __shared__ __align__(16) unsigned short As[128][40];
    __shared__ __align__(16) unsigned short Bs[128][40];

    const int rA = tid >> 3, kA = (tid & 7) * 4;
    const float* aPtr = X + (size_t)(bm * 128 + rA) * KDIM + kA;
    const int nB = (tid & 31) * 4, kB = (tid >> 5) * 4;
    const float* bPtr = W + (size_t)kB * NDIM + (size_t)bn * 128 + nB;

    float4v aReg[4], bReg[4];
#pragma unroll
    for (int p = 0; p < 4; ++p)
        aReg[p] = *reinterpret_cast<const float4v*>(aPtr + (size_t)(32 * p) * KDIM);
#pragma unroll
    for (int dk = 0; dk < 4; ++dk)
        bReg[dk] = *reinterpret_cast<const float4v*>(bPtr + (size_t)dk * NDIM);

    f32x4 acc[4][4];
#pragma unroll
    for (int i = 0; i < 4; ++i)
#pragma unroll
        for (int j = 0; j < 4; ++j) {
            acc[i][j][0] = 0.f; acc[i][j][1] = 0.f; acc[i][j][2] = 0.f; acc[i][j][3] = 0.f;
        }

    const int r16 = lane & 15, g8 = (lane >> 4) * 8;
    for (int kt = 0; kt < KDIM; kt += 32) {
#pragma unroll
        for (int p = 0; p < 4; ++p) {
            ushort4v v;
            v[0] = f2bf(aReg[p][0]); v[1] = f2bf(aReg[p][1]);
            v[2] = f2bf(aReg[p][2]); v[3] = f2bf(aReg[p][3]);
            *reinterpret_cast<ushort4v*>(&As[rA + 32 * p][kA]) = v;
        }
        unsigned short bb[4][4];
#pragma unroll
        for (int dk = 0; dk < 4; ++dk)
#pragma unroll
            for (int dn = 0; dn < 4; ++dn)
                bb[dn][dk] = (bReg[dk][dn] > 0.0f) ? (unsigned short)0x3F80u
                                                   : (unsigned short)0u;
#pragma unroll
        for (int dn = 0; dn < 4; ++dn) {
            ushort4v v;
            v[0] = bb[dn][0]; v[1] = bb[dn][1]; v[2] = bb[dn][2]; v[3] = bb[dn][3];
            *reinterpret_cast<ushort4v*>(&Bs[nB + dn][kB]) = v;
        }
        __syncthreads();
        if (kt + 32 < KDIM) {
#pragma unroll
            for (int p = 0; p < 4; ++p)
                aReg[p] = *reinterpret_cast<const float4v*>(
                    aPtr + (size_t)(32 * p) * KDIM + (kt + 32));
#pragma unroll
            for (int dk = 0; dk < 4; ++dk)
                bReg[dk] = *reinterpret_cast<const float4v*>(
                    bPtr + (size_t)(kt + 32 + dk) * NDIM);
        }
        short8 af[4], bfv[4];
#pragma unroll
        for (int mi = 0; mi < 4; ++mi)
            af[mi] = *reinterpret_cast<const short8*>(&As[wr * 64 + mi * 16 + r16][g8]);
#pragma unroll
        for (int ni = 0; ni < 4; ++ni)
            bfv[ni] = *reinterpret_cast<const short8*>(&Bs[wc * 64 + ni * 16 + r16][g8]);
#pragma unroll
        for (int mi = 0; mi < 4; ++mi)
#pragma unroll
            for (int ni = 0; ni < 4; ++ni)
                acc[mi][ni] = __builtin_amdgcn_mfma_f32_16x16x32_bf16(
                    af[mi], bfv[ni], acc[mi][ni], 0, 0, 0);
        __syncthreads();
    }

    const int orow0 = bm * 128 + wr * 64 + (lane >> 4) * 4;
    const int ocol0 = bn * 128 + wc * 64 + r16;
#pragma unroll
    for (int mi = 0; mi < 4; ++mi)
#pragma unroll
        for (int ni = 0; ni < 4; ++ni)
#pragma unroll
            for (int r = 0; r < 4; ++r)
                O[(size_t)(orow0 + mi * 16 + r) * NDIM + ocol0 + ni * 16] =
                    acc[mi][ni][r];
}

extern "C" void kernel_launch(void* const* d_in, const int* in_sizes, int n_in,
                              void* d_out, int out_size, void* d_ws, size_t ws_size,
                              hipStream_t stream) {
    const float* X = (const float*)d_in[0];
    const float* W = (const float*)d_in[1];
    float* O = (float*)d_out;
    (void)in_sizes; (void)n_in; (void)out_size;

    const size_t xq_bytes = (size_t)MDIM * KDIM;          // 16 MB
    const size_t wt_bytes = (size_t)NDIM * KDIM;          // 4 MB
    const size_t sc_bytes = (size_t)MDIM * sizeof(float); // 32 KB
    const size_t need = xq_bytes + wt_bytes + sc_bytes;

    if (ws_size >= need) {
        signed char* Xq = (signed char*)d_ws;
        signed char* Wt = Xq + xq_bytes;
        float* Sc = (float*)(Wt + wt_bytes);
        hipFuncSetAttribute((const void*)gemm_pv2,
                            hipFuncAttributeMaxDynamicSharedMemorySize, 98304);
        prep<<<dim3(MDIM + (KDIM / 64) * (NDIM / 64)), dim3(256), 0, stream>>>(X, W, Xq, Wt, Sc);
        gemm_pv2<<<dim3((MDIM / 256) * (NDIM / 256)), dim3(512), 98304, stream>>>(Xq, Wt, Sc, O);
    } else {
        binlin_fused<<<dim3((MDIM / 128) * (NDIM / 128)), dim3(256), 0, stream>>>(X, W, O);
    }
}

// Round 16
// 61.222 us; speedup vs baseline: 1.1664x; 1.1664x over previous
//
#include <hip/hip_runtime.h>

// BinaryLinear int8 path (round 16):
//   prep    : fused {X f32 -> i8 per-row quant + Sc} and {W -> {0,1} i8, NxK}
//   gemm_tri: 256x128 tile, 8 waves (4Mx2N, wave 64x64), BK=128 i8,
//             TRIPLE-buffered LDS (3 x 48KB), prefetch depth 2 ->
//             counted vmcnt(6) at tile top, NEVER drains in main loop
//             (T4 principle; every prior round drained vmcnt(0)/tile).
//             One barrier/tile. r8-proven XOR swizzle. mfma_i32_16x16x64_i8.
// Fallback: round-1 fused bf16 kernel if ws too small.

#define MDIM 8192
#define NDIM 2048
#define KDIM 2048
#define NT   (KDIM / 128)         // 16 K-tiles of 128 i8
#define CH   (64 * KDIM)          // chunk stride: 64 rows * 2048 B
#define BUF  49152                // LDS buffer stride (A 32K + B 16K)

typedef __attribute__((ext_vector_type(8))) short short8;
typedef __attribute__((ext_vector_type(4))) float float4v;
typedef __attribute__((ext_vector_type(4))) float f32x4;
typedef __attribute__((ext_vector_type(4))) int int4v;
typedef __attribute__((ext_vector_type(4))) unsigned short ushort4v;
typedef __attribute__((ext_vector_type(8))) unsigned short ushort8v;

__device__ __forceinline__ unsigned short f2bf(float f) {
    union { float f; unsigned u; } v; v.f = f;
    unsigned r = v.u + 0x7FFFu + ((v.u >> 16) & 1u);
    return (unsigned short)(r >> 16);
}

__device__ __forceinline__ void gload_lds16(void* l, const void* g) {
    __builtin_amdgcn_global_load_lds(
        (const __attribute__((address_space(1))) unsigned int*)g,
        (__attribute__((address_space(3))) unsigned int*)l,
        16, 0, 0);
}

#define FENCE asm volatile("" ::: "memory")
#define BAR do { FENCE; __builtin_amdgcn_s_barrier(); FENCE; } while (0)

// ---------------- pass 1 (fused): quantize X rows + binarize/transpose W ----
__global__ __launch_bounds__(256) void prep(const float* __restrict__ X,
                                            const float* __restrict__ W,
                                            signed char* __restrict__ Xq,
                                            signed char* __restrict__ Wt,
                                            float* __restrict__ Sc) {
    __shared__ __align__(16) signed char T[64][80];
    __shared__ float wm[4];
    const int t = threadIdx.x;
    const int bid = blockIdx.x;

    if (bid < MDIM) {
        const int row = bid;
        const float* xr = X + (size_t)row * KDIM + t * 8;
        float4v a = *reinterpret_cast<const float4v*>(xr);
        float4v b = *reinterpret_cast<const float4v*>(xr + 4);
        float m = fabsf(a[0]);
        m = fmaxf(m, fabsf(a[1])); m = fmaxf(m, fabsf(a[2])); m = fmaxf(m, fabsf(a[3]));
        m = fmaxf(m, fabsf(b[0])); m = fmaxf(m, fabsf(b[1]));
        m = fmaxf(m, fabsf(b[2])); m = fmaxf(m, fabsf(b[3]));
#pragma unroll
        for (int off = 32; off; off >>= 1)
            m = fmaxf(m, __shfl_xor(m, off));
        if ((t & 63) == 0) wm[t >> 6] = m;
        __syncthreads();
        const float s = fmaxf(fmaxf(wm[0], wm[1]), fmaxf(wm[2], wm[3]));
        const float inv = (s > 0.f) ? 127.0f / s : 0.f;

        int q[8];
        q[0] = __float2int_rn(a[0] * inv); q[1] = __float2int_rn(a[1] * inv);
        q[2] = __float2int_rn(a[2] * inv); q[3] = __float2int_rn(a[3] * inv);
        q[4] = __float2int_rn(b[0] * inv); q[5] = __float2int_rn(b[1] * inv);
        q[6] = __float2int_rn(b[2] * inv); q[7] = __float2int_rn(b[3] * inv);
        unsigned lo = (q[0] & 255) | ((q[1] & 255) << 8) | ((q[2] & 255) << 16) | ((unsigned)(q[3] & 255) << 24);
        unsigned hi = (q[4] & 255) | ((q[5] & 255) << 8) | ((q[6] & 255) << 16) | ((unsigned)(q[7] & 255) << 24);
        unsigned* dst = (unsigned*)(Xq + (size_t)row * KDIM + t * 8);
        dst[0] = lo; dst[1] = hi;
        if (t == 0) Sc[row] = s * (1.0f / 127.0f);
    } else {
        const int wb = bid - MDIM;
        const int k0 = (wb >> 5) * 64;
        const int n0 = (wb & 31) * 64;
        const int kr = t >> 4;
        const int nc = (t & 15) * 4;
#pragma unroll
        for (int rr = 0; rr < 4; ++rr) {
            int k = k0 + rr * 16 + kr;
            float4v w4 = *reinterpret_cast<const float4v*>(W + (size_t)k * NDIM + n0 + nc);
#pragma unroll
            for (int c = 0; c < 4; ++c)
                T[nc + c][rr * 16 + kr] = (w4[c] > 0.0f) ? (signed char)1 : (signed char)0;
        }
        __syncthreads();
        const int row = t >> 2, ch = t & 3;
        int4v v = *reinterpret_cast<const int4v*>(&T[row][ch * 16]);
        *reinterpret_cast<int4v*>(Wt + (size_t)(n0 + row) * KDIM + k0 + ch * 16) = v;
    }
}

// ---------------- pass 2: 256x128 i8 GEMM, tri-buffer never-drain ----------------
// LDS buffer b (48 KB): A [256 rows][128 B] at +0, B [128 rows][128 B] at
// +32768; 3 buffers. 16B slot s of row r holds global k-octet s^(r&7)
// (pre-swizzled source, dest linear — r8-proven, 0 conflicts).
// Wave w: wr=w>>1 (0..3), wc=w&1; wave tile 64x64 = 4mi x 4ni, 2 ks.
// Prologue stages T0->b0, T1->b1. Tile t (buf t%3):
//   vmcnt(6)  [retires own 6 loads of tile t; tile t+1's 6 stay in flight;
//              last tile: vmcnt(0)]
//   BAR       [all waves' slices of buf complete; prev readers of the
//              buffer being overwritten below are done]
//   stage tile t+2 -> buf (t+2)%3   (6 gload_lds; skipped near end)
//   8 reads ks0; 16 MFMA; 8 reads ks1; 16 MFMA (setprio)
__global__ __launch_bounds__(512, 1) void gemm_tri(const signed char* __restrict__ A,
                                                   const signed char* __restrict__ Bt,
                                                   const float* __restrict__ Sc,
                                                   float* __restrict__ O) {
    extern __shared__ char lds[];
    const int tid  = threadIdx.x;
    const int lane = tid & 63;
    const int w    = tid >> 6;       // 0..7
    const int wr   = w >> 1;         // 0..3
    const int wc   = w & 1;          // 0..1

    int id  = blockIdx.x;            // 512 blocks, %8==0 -> bijective
    int swz = (id & 7) * 64 + (id >> 3);
    const int bm = swz >> 4;         // 0..31
    const int bn = swz & 15;         // 0..15

    // staging source: lane l -> row (w*8 + l>>3), pre-swizzled slot ((l&7)^(l>>3))
    const int l3 = lane >> 3, l7 = lane & 7;
    const int srcOff = (w * 8 + l3) * KDIM + ((l7 ^ l3) << 4);
    const char* gA = (const char*)A + (size_t)(bm * 256) * KDIM + srcOff;
    const char* gB = (const char*)Bt + (size_t)(bn * 128) * KDIM + srcOff;

    // fragment read constants: lane l -> row l&15, 16 k-bytes at slot l>>4
    const int fr = lane & 15, fg = lane >> 4;
    const int se0 = ((fg)     ^ (fr & 7)) << 4;   // ks0: slots 0-3
    const int se1 = ((4 + fg) ^ (fr & 7)) << 4;   // ks1: slots 4-7
    const int aRd = (wr * 64 + fr) * 128;         // + buf + mi*2048 + se
    const int bRd = 32768 + (wc * 64 + fr) * 128; // + buf + ni*2048 + se

    int4v acc[4][4];
#pragma unroll
    for (int i = 0; i < 4; ++i)
#pragma unroll
        for (int j = 0; j < 4; ++j) {
            acc[i][j][0] = 0; acc[i][j][1] = 0; acc[i][j][2] = 0; acc[i][j][3] = 0;
        }

    // prologue: stage T0 -> buf0, T1 -> buf1 (6 instrs each, per wave)
#pragma unroll
    for (int c = 0; c < 4; ++c)
        gload_lds16(lds + c * 8192 + w * 1024, gA + (size_t)c * CH);
#pragma unroll
    for (int c = 0; c < 2; ++c)
        gload_lds16(lds + 32768 + c * 8192 + w * 1024, gB + (size_t)c * CH);
#pragma unroll
    for (int c = 0; c < 4; ++c)
        gload_lds16(lds + BUF + c * 8192 + w * 1024, gA + 128 + (size_t)c * CH);
#pragma unroll
    for (int c = 0; c < 2; ++c)
        gload_lds16(lds + BUF + 32768 + c * 8192 + w * 1024, gB + 128 + (size_t)c * CH);

    int b3 = 0;                       // t % 3
    int s3 = 2;                       // (t+2) % 3
    for (int t = 0; t < NT; ++t) {
        const int cur = b3 * BUF;
        const bool moreS = (t + 2 < NT);

        // counted wait: retire own 6 loads of tile t; keep tile t+1's flying.
        if (t == NT - 1) asm volatile("s_waitcnt vmcnt(0)" ::: "memory");
        else             asm volatile("s_waitcnt vmcnt(6)" ::: "memory");
        BAR;

        // ---- stage tile t+2 into buf (t+2)%3 ----
        if (moreS) {
            const int st = s3 * BUF;
            const char* aN = gA + (size_t)(t + 2) * 128;
            const char* bN = gB + (size_t)(t + 2) * 128;
#pragma unroll
            for (int c = 0; c < 4; ++c)
                gload_lds16(lds + st + c * 8192 + w * 1024, aN + (size_t)c * CH);
#pragma unroll
            for (int c = 0; c < 2; ++c)
                gload_lds16(lds + st + 32768 + c * 8192 + w * 1024, bN + (size_t)c * CH);
        }

        // ---- ks0: 8 frag reads + 16 MFMA ----
        int4v af[4], bf[4];
#pragma unroll
        for (int mi = 0; mi < 4; ++mi)
            af[mi] = *reinterpret_cast<const int4v*>(lds + cur + aRd + mi * 2048 + se0);
#pragma unroll
        for (int ni = 0; ni < 4; ++ni)
            bf[ni] = *reinterpret_cast<const int4v*>(lds + cur + bRd + ni * 2048 + se0);
        __builtin_amdgcn_s_setprio(1);
#pragma unroll
        for (int mi = 0; mi < 4; ++mi)
#pragma unroll
            for (int ni = 0; ni < 4; ++ni)
                acc[mi][ni] = __builtin_amdgcn_mfma_i32_16x16x64_i8(
                    af[mi], bf[ni], acc[mi][ni], 0, 0, 0);
        __builtin_amdgcn_s_setprio(0);

        // ---- ks1: 8 frag reads + 16 MFMA ----
#pragma unroll
        for (int mi = 0; mi < 4; ++mi)
            af[mi] = *reinterpret_cast<const int4v*>(lds + cur + aRd + mi * 2048 + se1);
#pragma unroll
        for (int ni = 0; ni < 4; ++ni)
            bf[ni] = *reinterpret_cast<const int4v*>(lds + cur + bRd + ni * 2048 + se1);
        __builtin_amdgcn_s_setprio(1);
#pragma unroll
        for (int mi = 0; mi < 4; ++mi)
#pragma unroll
            for (int ni = 0; ni < 4; ++ni)
                acc[mi][ni] = __builtin_amdgcn_mfma_i32_16x16x64_i8(
                    af[mi], bf[ni], acc[mi][ni], 0, 0, 0);
        __builtin_amdgcn_s_setprio(0);
        FENCE;

        b3 = (b3 == 2) ? 0 : b3 + 1;
        s3 = (s3 == 2) ? 0 : s3 + 1;
    }

    // ---- epilogue: C/D col = lane&15, row = 4*(lane>>4) + reg; dequant ----
    const int orow0 = bm * 256 + wr * 64 + fg * 4;
    const int ocol0 = bn * 128 + wc * 64 + fr;
#pragma unroll
    for (int mi = 0; mi < 4; ++mi)
#pragma unroll
        for (int r = 0; r < 4; ++r) {
            const int row = orow0 + mi * 16 + r;
            const float s = Sc[row];
            float* op = O + (size_t)row * NDIM + ocol0;
#pragma unroll
            for (int ni = 0; ni < 4; ++ni)
                op[ni * 16] = s * (float)acc[mi][ni][r];
        }
}

// ---------------- fallback: round-1 fused bf16 kernel ----------------
__global__ __launch_bounds__(256, 2) void binlin_fused(
        const float* __restrict__ X, const float* __restrict__ W,
        float* __restrict__ O) {
    const int tid = threadIdx.x;
    const int lane = tid & 63;
    const int wave = tid >> 6;
    const int wr = wave >> 1, wc = wave & 1;
    const int NWG = (MDIM / 128) * (NDIM / 128);
    int id = blockIdx.x;
    int swz = (id & 7) * (NWG >> 3) + (id >> 3);
    const int bm = swz >> 4, bn = swz & 15;

    __shared__ __align__(16) unsigned short As[128][40];
    __shared__ __align__(16) unsigned short Bs[128][40];

    const int rA = tid >> 3, kA = (tid & 7) * 4;
    const float* aPtr = X + (size_t)(bm * 128 + rA) * KDIM + kA;
    const int nB = (tid & 31) * 4, kB = (tid >> 5) * 4;
    const float* bPtr = W + (size_t)kB * NDIM + (size_t)bn * 128 + nB;

    float4v aReg[4], bReg[4];
#pragma unroll
    for (int p = 0; p < 4; ++p)
        aReg[p] = *reinterpret_cast<const float4v*>(aPtr + (size_t)(32 * p) * KDIM);
#pragma unroll
    for (int dk = 0; dk < 4; ++dk)
        bReg[dk] = *reinterpret_cast<const float4v*>(bPtr + (size_t)dk * NDIM);

    f32x4 acc[4][4];
#pragma unroll
    for (int i = 0; i < 4; ++i)
#pragma unroll
        for (int j = 0; j < 4; ++j) {
            acc[i][j][0] = 0.f; acc[i][j][1] = 0.f; acc[i][j][2] = 0.f; acc[i][j][3] = 0.f;
        }

    const int r16 = lane & 15, g8 = (lane >> 4) * 8;
    for (int kt = 0; kt < KDIM; kt += 32) {
#pragma unroll
        for (int p = 0; p < 4; ++p) {
            ushort4v v;
            v[0] = f2bf(aReg[p][0]); v[1] = f2bf(aReg[p][1]);
            v[2] = f2bf(aReg[p][2]); v[3] = f2bf(aReg[p][3]);
            *reinterpret_cast<ushort4v*>(&As[rA + 32 * p][kA]) = v;
        }
        unsigned short bb[4][4];
#pragma unroll
        for (int dk = 0; dk < 4; ++dk)
#pragma unroll
            for (int dn = 0; dn < 4; ++dn)
                bb[dn][dk] = (bReg[dk][dn] > 0.0f) ? (unsigned short)0x3F80u
                                                   : (unsigned short)0u;
#pragma unroll
        for (int dn = 0; dn < 4; ++dn) {
            ushort4v v;
            v[0] = bb[dn][0]; v[1] = bb[dn][1]; v[2] = bb[dn][2]; v[3] = bb[dn][3];
            *reinterpret_cast<ushort4v*>(&Bs[nB + dn][kB]) = v;
        }
        __syncthreads();
        if (kt + 32 < KDIM) {
#pragma unroll
            for (int p = 0; p < 4; ++p)
                aReg[p] = *reinterpret_cast<const float4v*>(
                    aPtr + (size_t)(32 * p) * KDIM + (kt + 32));
#pragma unroll
            for (int dk = 0; dk < 4; ++dk)
                bReg[dk] = *reinterpret_cast<const float4v*>(
                    bPtr + (size_t)(kt + 32 + dk) * NDIM);
        }
        short8 af[4], bfv[4];
#pragma unroll
        for (int mi = 0; mi < 4; ++mi)
            af[mi] = *reinterpret_cast<const short8*>(&As[wr * 64 + mi * 16 + r16][g8]);
#pragma unroll
        for (int ni = 0; ni < 4; ++ni)
            bfv[ni] = *reinterpret_cast<const short8*>(&Bs[wc * 64 + ni * 16 + r16][g8]);
#pragma unroll
        for (int mi = 0; mi < 4; ++mi)
#pragma unroll
            for (int ni = 0; ni < 4; ++ni)
                acc[mi][ni] = __builtin_amdgcn_mfma_f32_16x16x32_bf16(
                    af[mi], bfv[ni], acc[mi][ni], 0, 0, 0);
        __syncthreads();
    }

    const int orow0 = bm * 128 + wr * 64 + (lane >> 4) * 4;
    const int ocol0 = bn * 128 + wc * 64 + r16;
#pragma unroll
    for (int mi = 0; mi < 4; ++mi)
#pragma unroll
        for (int ni = 0; ni < 4; ++ni)
#pragma unroll
            for (int r = 0; r < 4; ++r)
                O[(size_t)(orow0 + mi * 16 + r) * NDIM + ocol0 + ni * 16] =
                    acc[mi][ni][r];
}

extern "C" void kernel_launch(void* const* d_in, const int* in_sizes, int n_in,
                              void* d_out, int out_size, void* d_ws, size_t ws_size,
                              hipStream_t stream) {
    const float* X = (const float*)d_in[0];
    const float* W = (const float*)d_in[1];
    float* O = (float*)d_out;
    (void)in_sizes; (void)n_in; (void)out_size;

    const size_t xq_bytes = (size_t)MDIM * KDIM;          // 16 MB
    const size_t wt_bytes = (size_t)NDIM * KDIM;          // 4 MB
    const size_t sc_bytes = (size_t)MDIM * sizeof(float); // 32 KB
    const size_t need = xq_bytes + wt_bytes + sc_bytes;

    if (ws_size >= need) {
        signed char* Xq = (signed char*)d_ws;
        signed char* Wt = Xq + xq_bytes;
        float* Sc = (float*)(Wt + wt_bytes);
        hipFuncSetAttribute((const void*)gemm_tri,
                            hipFuncAttributeMaxDynamicSharedMemorySize, 3 * BUF);
        prep<<<dim3(MDIM + (KDIM / 64) * (NDIM / 64)), dim3(256), 0, stream>>>(X, W, Xq, Wt, Sc);
        gemm_tri<<<dim3((MDIM / 256) * (NDIM / 128)), dim3(512), 3 * BUF, stream>>>(Xq, Wt, Sc, O);
    } else {
        binlin_fused<<<dim3((MDIM / 128) * (NDIM / 128)), dim3(256), 0, stream>>>(X, W, O);
    }
}

// Round 17
// 59.942 us; speedup vs baseline: 1.1913x; 1.0214x over previous
//
#include <hip/hip_runtime.h>

// BinaryLinear int8 path (round 17):
//   prep    : fused {X f32 -> i8 per-row quant + Sc} and {W -> {0,1} i8, NxK}
//   gemm_big: 256x256 tile, 4 waves (2x2), wave tile 128x128 (HALVES LDS
//             reads per FLOP vs all prior rounds: 8 vs 12 reads/Mop ->
//             first config where MFMA/SIMD >= LDS-port/CU), BK=128, dbuf
//             128KB LDS, 1 wave/SIMD (acc 256 regs in unified AGPR file),
//             r8-proven swizzle + 1-barrier loop, mfma_i32_16x16x64_i8.
// Fallback: round-1 fused bf16 kernel if ws too small.

#define MDIM 8192
#define NDIM 2048
#define KDIM 2048
#define NT   (KDIM / 128)         // 16 K-tiles of 128 i8

typedef __attribute__((ext_vector_type(8))) short short8;
typedef __attribute__((ext_vector_type(4))) float float4v;
typedef __attribute__((ext_vector_type(4))) float f32x4;
typedef __attribute__((ext_vector_type(4))) int int4v;
typedef __attribute__((ext_vector_type(4))) unsigned short ushort4v;
typedef __attribute__((ext_vector_type(8))) unsigned short ushort8v;

__device__ __forceinline__ unsigned short f2bf(float f) {
    union { float f; unsigned u; } v; v.f = f;
    unsigned r = v.u + 0x7FFFu + ((v.u >> 16) & 1u);
    return (unsigned short)(r >> 16);
}

__device__ __forceinline__ void gload_lds16(void* l, const void* g) {
    __builtin_amdgcn_global_load_lds(
        (const __attribute__((address_space(1))) unsigned int*)g,
        (__attribute__((address_space(3))) unsigned int*)l,
        16, 0, 0);
}

#define FENCE asm volatile("" ::: "memory")
#define BAR do { FENCE; __builtin_amdgcn_s_barrier(); FENCE; } while (0)

// ---------------- pass 1 (fused): quantize X rows + binarize/transpose W ----
__global__ __launch_bounds__(256) void prep(const float* __restrict__ X,
                                            const float* __restrict__ W,
                                            signed char* __restrict__ Xq,
                                            signed char* __restrict__ Wt,
                                            float* __restrict__ Sc) {
    __shared__ __align__(16) signed char T[64][80];
    __shared__ float wm[4];
    const int t = threadIdx.x;
    const int bid = blockIdx.x;

    if (bid < MDIM) {
        const int row = bid;
        const float* xr = X + (size_t)row * KDIM + t * 8;
        float4v a = *reinterpret_cast<const float4v*>(xr);
        float4v b = *reinterpret_cast<const float4v*>(xr + 4);
        float m = fabsf(a[0]);
        m = fmaxf(m, fabsf(a[1])); m = fmaxf(m, fabsf(a[2])); m = fmaxf(m, fabsf(a[3]));
        m = fmaxf(m, fabsf(b[0])); m = fmaxf(m, fabsf(b[1]));
        m = fmaxf(m, fabsf(b[2])); m = fmaxf(m, fabsf(b[3]));
#pragma unroll
        for (int off = 32; off; off >>= 1)
            m = fmaxf(m, __shfl_xor(m, off));
        if ((t & 63) == 0) wm[t >> 6] = m;
        __syncthreads();
        const float s = fmaxf(fmaxf(wm[0], wm[1]), fmaxf(wm[2], wm[3]));
        const float inv = (s > 0.f) ? 127.0f / s : 0.f;

        int q[8];
        q[0] = __float2int_rn(a[0] * inv); q[1] = __float2int_rn(a[1] * inv);
        q[2] = __float2int_rn(a[2] * inv); q[3] = __float2int_rn(a[3] * inv);
        q[4] = __float2int_rn(b[0] * inv); q[5] = __float2int_rn(b[1] * inv);
        q[6] = __float2int_rn(b[2] * inv); q[7] = __float2int_rn(b[3] * inv);
        unsigned lo = (q[0] & 255) | ((q[1] & 255) << 8) | ((q[2] & 255) << 16) | ((unsigned)(q[3] & 255) << 24);
        unsigned hi = (q[4] & 255) | ((q[5] & 255) << 8) | ((q[6] & 255) << 16) | ((unsigned)(q[7] & 255) << 24);
        unsigned* dst = (unsigned*)(Xq + (size_t)row * KDIM + t * 8);
        dst[0] = lo; dst[1] = hi;
        if (t == 0) Sc[row] = s * (1.0f / 127.0f);
    } else {
        const int wb = bid - MDIM;
        const int k0 = (wb >> 5) * 64;
        const int n0 = (wb & 31) * 64;
        const int kr = t >> 4;
        const int nc = (t & 15) * 4;
#pragma unroll
        for (int rr = 0; rr < 4; ++rr) {
            int k = k0 + rr * 16 + kr;
            float4v w4 = *reinterpret_cast<const float4v*>(W + (size_t)k * NDIM + n0 + nc);
#pragma unroll
            for (int c = 0; c < 4; ++c)
                T[nc + c][rr * 16 + kr] = (w4[c] > 0.0f) ? (signed char)1 : (signed char)0;
        }
        __syncthreads();
        const int row = t >> 2, ch = t & 3;
        int4v v = *reinterpret_cast<const int4v*>(&T[row][ch * 16]);
        *reinterpret_cast<int4v*>(Wt + (size_t)(n0 + row) * KDIM + k0 + ch * 16) = v;
    }
}

// ---------------- pass 2: 256x256 i8 GEMM, 128x128 wave tiles ----------------
// LDS per buffer (64 KB): A [256 rows][128 B] at +0, B [256 rows][128 B] at
// +32768; dbuf (128 KB total). 16B slot s of row r holds global k-octet
// s^(r&7) (pre-swizzled source, linear dest — r8-proven, 0 conflicts).
// 4 waves 2x2: wave tile 128x128 = 8mi x 8ni 16x16x64 frags, 2 ks.
// Stage per wave: A rows [w*64, w*64+64) via 8 instrs (8 rows each) + same
// for B. Per tile: vmcnt(0); BAR; stage 16 into nxt; {read A8+B8; 64 MFMA}
// x 2 ks (setprio). acc[8][8] (256 regs) lives in the unified AGPR file.
__global__ __launch_bounds__(256, 1) void gemm_big(const signed char* __restrict__ A,
                                                   const signed char* __restrict__ Bt,
                                                   const float* __restrict__ Sc,
                                                   float* __restrict__ O) {
    extern __shared__ char lds[];
    const int tid  = threadIdx.x;
    const int lane = tid & 63;
    const int w    = tid >> 6;       // 0..3
    const int wr   = w >> 1;         // 0..1
    const int wc   = w & 1;          // 0..1

    int id  = blockIdx.x;            // 256 blocks, %8==0 -> bijective
    int swz = (id & 7) * 32 + (id >> 3);
    const int bm = swz >> 3;         // 0..31
    const int bn = swz & 7;          // 0..7

    // staging source: lane l -> row (w*64 + l>>3 [+8 per instr]), slot ((l&7)^(l>>3))
    const int l3 = lane >> 3, l7 = lane & 7;
    const int srcOff = (w * 64 + l3) * KDIM + ((l7 ^ l3) << 4);
    const char* gA = (const char*)A + (size_t)(bm * 256) * KDIM + srcOff;
    const char* gB = (const char*)Bt + (size_t)(bn * 256) * KDIM + srcOff;
    const int ldsA = (w * 64) * 128;           // + i*1024 (8 rows per instr)
    const int ldsB = 32768 + (w * 64) * 128;

    // fragment read constants: lane l -> row l&15, 16 k-bytes at slot l>>4
    const int fr = lane & 15, fg = lane >> 4;
    const int se0 = ((fg)     ^ (fr & 7)) << 4;   // ks0: slots 0-3
    const int se1 = ((4 + fg) ^ (fr & 7)) << 4;   // ks1: slots 4-7
    const int aRd = (wr * 128 + fr) * 128;        // + buf + mi*2048 + se
    const int bRd = 32768 + (wc * 128 + fr) * 128;// + buf + ni*2048 + se

    int4v acc[8][8];
#pragma unroll
    for (int i = 0; i < 8; ++i)
#pragma unroll
        for (int j = 0; j < 8; ++j) {
            acc[i][j][0] = 0; acc[i][j][1] = 0; acc[i][j][2] = 0; acc[i][j][3] = 0;
        }

    // prologue: stage tile 0 into buf 0
#pragma unroll
    for (int i = 0; i < 8; ++i)
        gload_lds16(lds + ldsA + i * 1024, gA + (size_t)i * 8 * KDIM);
#pragma unroll
    for (int i = 0; i < 8; ++i)
        gload_lds16(lds + ldsB + i * 1024, gB + (size_t)i * 8 * KDIM);

    for (int t = 0; t < NT; ++t) {
        const int cur = (t & 1) << 16;
        const int nxt = ((t + 1) & 1) << 16;
        const bool more = (t + 1 < NT);
        const char* aN = gA + (size_t)(t + 1) * 128;
        const char* bN = gB + (size_t)(t + 1) * 128;

        // staged loads for buffer cur landed (issued a full tile ago)
        asm volatile("s_waitcnt vmcnt(0)" ::: "memory");
        BAR;

        // ---- stage tile t+1 into nxt (16 gload_lds per wave) ----
        if (more) {
#pragma unroll
            for (int i = 0; i < 8; ++i)
                gload_lds16(lds + nxt + ldsA + i * 1024, aN + (size_t)i * 8 * KDIM);
#pragma unroll
            for (int i = 0; i < 8; ++i)
                gload_lds16(lds + nxt + ldsB + i * 1024, bN + (size_t)i * 8 * KDIM);
        }

        // ---- ks0: read A8 + B8, 64 MFMA ----
        {
            int4v af[8], bf[8];
#pragma unroll
            for (int mi = 0; mi < 8; ++mi)
                af[mi] = *reinterpret_cast<const int4v*>(lds + cur + aRd + mi * 2048 + se0);
#pragma unroll
            for (int ni = 0; ni < 8; ++ni)
                bf[ni] = *reinterpret_cast<const int4v*>(lds + cur + bRd + ni * 2048 + se0);
            __builtin_amdgcn_s_setprio(1);
#pragma unroll
            for (int mi = 0; mi < 8; ++mi)
#pragma unroll
                for (int ni = 0; ni < 8; ++ni)
                    acc[mi][ni] = __builtin_amdgcn_mfma_i32_16x16x64_i8(
                        af[mi], bf[ni], acc[mi][ni], 0, 0, 0);
            __builtin_amdgcn_s_setprio(0);
        }

        // ---- ks1: read A8 + B8, 64 MFMA ----
        {
            int4v af[8], bf[8];
#pragma unroll
            for (int mi = 0; mi < 8; ++mi)
                af[mi] = *reinterpret_cast<const int4v*>(lds + cur + aRd + mi * 2048 + se1);
#pragma unroll
            for (int ni = 0; ni < 8; ++ni)
                bf[ni] = *reinterpret_cast<const int4v*>(lds + cur + bRd + ni * 2048 + se1);
            __builtin_amdgcn_s_setprio(1);
#pragma unroll
            for (int mi = 0; mi < 8; ++mi)
#pragma unroll
                for (int ni = 0; ni < 8; ++ni)
                    acc[mi][ni] = __builtin_amdgcn_mfma_i32_16x16x64_i8(
                        af[mi], bf[ni], acc[mi][ni], 0, 0, 0);
            __builtin_amdgcn_s_setprio(0);
        }
        FENCE;
    }

    // ---- epilogue: C/D col = lane&15, row = 4*(lane>>4) + reg; dequant ----
    const int orow0 = bm * 256 + wr * 128 + fg * 4;
    const int ocol0 = bn * 256 + wc * 128 + fr;
#pragma unroll
    for (int mi = 0; mi < 8; ++mi)
#pragma unroll
        for (int r = 0; r < 4; ++r) {
            const int row = orow0 + mi * 16 + r;
            const float s = Sc[row];
            float* op = O + (size_t)row * NDIM + ocol0;
#pragma unroll
            for (int ni = 0; ni < 8; ++ni)
                op[ni * 16] = s * (float)acc[mi][ni][r];
        }
}

// ---------------- fallback: round-1 fused bf16 kernel ----------------
__global__ __launch_bounds__(256, 2) void binlin_fused(
        const float* __restrict__ X, const float* __restrict__ W,
        float* __restrict__ O) {
    const int tid = threadIdx.x;
    const int lane = tid & 63;
    const int wave = tid >> 6;
    const int wr = wave >> 1, wc = wave & 1;
    const int NWG = (MDIM / 128) * (NDIM / 128);
    int id = blockIdx.x;
    int swz = (id & 7) * (NWG >> 3) + (id >> 3);
    const int bm = swz >> 4, bn = swz & 15;

    __shared__ __align__(16) unsigned short As[128][40];
    __shared__ __align__(16) unsigned short Bs[128][40];

    const int rA = tid >> 3, kA = (tid & 7) * 4;
    const float* aPtr = X + (size_t)(bm * 128 + rA) * KDIM + kA;
    const int nB = (tid & 31) * 4, kB = (tid >> 5) * 4;
    const float* bPtr = W + (size_t)kB * NDIM + (size_t)bn * 128 + nB;

    float4v aReg[4], bReg[4];
#pragma unroll
    for (int p = 0; p < 4; ++p)
        aReg[p] = *reinterpret_cast<const float4v*>(aPtr + (size_t)(32 * p) * KDIM);
#pragma unroll
    for (int dk = 0; dk < 4; ++dk)
        bReg[dk] = *reinterpret_cast<const float4v*>(bPtr + (size_t)dk * NDIM);

    f32x4 acc[4][4];
#pragma unroll
    for (int i = 0; i < 4; ++i)
#pragma unroll
        for (int j = 0; j < 4; ++j) {
            acc[i][j][0] = 0.f; acc[i][j][1] = 0.f; acc[i][j][2] = 0.f; acc[i][j][3] = 0.f;
        }

    const int r16 = lane & 15, g8 = (lane >> 4) * 8;
    for (int kt = 0; kt < KDIM; kt += 32) {
#pragma unroll
        for (int p = 0; p < 4; ++p) {
            ushort4v v;
            v[0] = f2bf(aReg[p][0]); v[1] = f2bf(aReg[p][1]);
            v[2] = f2bf(aReg[p][2]); v[3] = f2bf(aReg[p][3]);
            *reinterpret_cast<ushort4v*>(&As[rA + 32 * p][kA]) = v;
        }
        unsigned short bb[4][4];
#pragma unroll
        for (int dk = 0; dk < 4; ++dk)
#pragma unroll
            for (int dn = 0; dn < 4; ++dn)
                bb[dn][dk] = (bReg[dk][dn] > 0.0f) ? (unsigned short)0x3F80u
                                                   : (unsigned short)0u;
#pragma unroll
        for (int dn = 0; dn < 4; ++dn) {
            ushort4v v;
            v[0] = bb[dn][0]; v[1] = bb[dn][1]; v[2] = bb[dn][2]; v[3] = bb[dn][3];
            *reinterpret_cast<ushort4v*>(&Bs[nB + dn][kB]) = v;
        }
        __syncthreads();
        if (kt + 32 < KDIM) {
#pragma unroll
            for (int p = 0; p < 4; ++p)
                aReg[p] = *reinterpret_cast<const float4v*>(
                    aPtr + (size_t)(32 * p) * KDIM + (kt + 32));
#pragma unroll
            for (int dk = 0; dk < 4; ++dk)
                bReg[dk] = *reinterpret_cast<const float4v*>(
                    bPtr + (size_t)(kt + 32 + dk) * NDIM);
        }
        short8 af[4], bfv[4];
#pragma unroll
        for (int mi = 0; mi < 4; ++mi)
            af[mi] = *reinterpret_cast<const short8*>(&As[wr * 64 + mi * 16 + r16][g8]);
#pragma unroll
        for (int ni = 0; ni < 4; ++ni)
            bfv[ni] = *reinterpret_cast<const short8*>(&Bs[wc * 64 + ni * 16 + r16][g8]);
#pragma unroll
        for (int mi = 0; mi < 4; ++mi)
#pragma unroll
            for (int ni = 0; ni < 4; ++ni)
                acc[mi][ni] = __builtin_amdgcn_mfma_f32_16x16x32_bf16(
                    af[mi], bfv[ni], acc[mi][ni], 0, 0, 0);
        __syncthreads();
    }

    const int orow0 = bm * 128 + wr * 64 + (lane >> 4) * 4;
    const int ocol0 = bn * 128 + wc * 64 + r16;
#pragma unroll
    for (int mi = 0; mi < 4; ++mi)
#pragma unroll
        for (int ni = 0; ni < 4; ++ni)
#pragma unroll
            for (int r = 0; r < 4; ++r)
                O[(size_t)(orow0 + mi * 16 + r) * NDIM + ocol0 + ni * 16] =
                    acc[mi][ni][r];
}

extern "C" void kernel_launch(void* const* d_in, const int* in_sizes, int n_in,
                              void* d_out, int out_size, void* d_ws, size_t ws_size,
                              hipStream_t stream) {
    const float* X = (const float*)d_in[0];
    const float* W = (const float*)d_in[1];
    float* O = (float*)d_out;
    (void)in_sizes; (void)n_in; (void)out_size;

    const size_t xq_bytes = (size_t)MDIM * KDIM;          // 16 MB
    const size_t wt_bytes = (size_t)NDIM * KDIM;          // 4 MB
    const size_t sc_bytes = (size_t)MDIM * sizeof(float); // 32 KB
    const size_t need = xq_bytes + wt_bytes + sc_bytes;

    if (ws_size >= need) {
        signed char* Xq = (signed char*)d_ws;
        signed char* Wt = Xq + xq_bytes;
        float* Sc = (float*)(Wt + wt_bytes);
        hipFuncSetAttribute((const void*)gemm_big,
                            hipFuncAttributeMaxDynamicSharedMemorySize, 131072);
        prep<<<dim3(MDIM + (KDIM / 64) * (NDIM / 64)), dim3(256), 0, stream>>>(X, W, Xq, Wt, Sc);
        gemm_big<<<dim3((MDIM / 256) * (NDIM / 256)), dim3(256), 131072, stream>>>(Xq, Wt, Sc, O);
    } else {
        binlin_fused<<<dim3((MDIM / 128) * (NDIM / 128)), dim3(256), 0, stream>>>(X, W, O);
    }
}